// Round 6
// baseline (446.508 us; speedup 1.0000x reference)
//
#include <hip/hip_runtime.h>
#include <hip/hip_bf16.h>

// GNN attention layer: edge logits -> segment softmax(dst) -> weighted gather of
// hv=x@Wproj.T -> elu -> GRUCell(context, x) -> relu.
// V=50000, E=800000, D=H=128. Inputs f32 (proven R3/R4), OUTPUT f32 (R5 insight:
// absmax was compute-independent == we were writing bf16 into an f32 buffer,
// leaving the top half zero). src/dst int32.
//
// Pipeline (all on `stream`):
//   P  probe x dtype (f32 vs bf16) -> g_is_bf16   (robustness)
//   C1 convert x -> g_xbf (bf16)
//   C2 convert W_edge/W_proj/W_ih/W_hh/biases -> g_wsmall (bf16)
//   K0 zero counts
//   K1 node_pre:  MFMA per 16-node tile -> hv (bf16), pd, ps
//   K2 histogram of dst
//   K3 single-block exclusive scan -> row_off, cursor
//   K4 edge scatter: w=exp(leaky(pd[dst]+ps[src]+b)), CSR-sorted (src, w)
//   K5 aggregate: wave per dst node, acc = sum w*hv[src]; ctx = elu(acc/sum w)
//   K6 gru: MFMA gates, residual from ORIGINAL f32 x, f32 out, NaN-canary relu

#define V_NODES 50000
#define E_EDGES 800000
#define D_FEAT  128

typedef short bf16x8 __attribute__((ext_vector_type(8)));  // 8 bf16 in 4 VGPRs
typedef float f32x4  __attribute__((ext_vector_type(4)));
typedef unsigned short u16x4 __attribute__((ext_vector_type(4)));

// small-tensor bf16 pool element offsets
#define OFF_WEDGE 0
#define OFF_WPROJ 256
#define OFF_WIH   16640
#define OFF_WHH   65792
#define OFF_BEDGE 114944
#define OFF_BPROJ 114945
#define OFF_BIH   115073
#define OFF_BHH   115457
#define SMALL_TOTAL 115841

// ---- device-global scratch (~46 MB; immune to ws_size) ----
__device__ int   g_is_bf16;
__device__ float g_pd[V_NODES];
__device__ float g_ps[V_NODES];
__device__ int   g_counts[V_NODES];
__device__ int   g_row_off[V_NODES + 1];
__device__ int   g_cursor[V_NODES];
__device__ int   g_s_src[E_EDGES];
__device__ float g_s_val[E_EDGES];
__device__ __attribute__((aligned(16))) unsigned short g_xbf[V_NODES * D_FEAT];
__device__ __attribute__((aligned(16))) unsigned short g_wsmall[SMALL_TOTAL + 15];
__device__ __attribute__((aligned(16))) unsigned short g_hv[V_NODES * D_FEAT];
__device__ __attribute__((aligned(16))) unsigned short g_ctx[V_NODES * D_FEAT];

static __device__ __forceinline__ float b2f(unsigned short u) {
  union { unsigned int i; float f; } v; v.i = ((unsigned int)u) << 16; return v.f;
}
static __device__ __forceinline__ unsigned short f2b(float f) {
  unsigned int i = __float_as_uint(f);
  unsigned int r = (i + 0x7FFFu + ((i >> 16) & 1u)) >> 16;  // RNE (NaN stays NaN)
  return (unsigned short)r;
}
static __device__ __forceinline__ bf16x8 load_frag(const unsigned short* p) {
  return *reinterpret_cast<const bf16x8*>(p);  // 16B-aligned vector load
}

// ---------------- P: dtype probe on x ----------------------------------------
__global__ void probe_kernel(const unsigned int* __restrict__ x)
{
  __shared__ int cnt;
  if (threadIdx.x == 0) cnt = 0;
  __syncthreads();
  const unsigned int w  = x[threadIdx.x];
  const unsigned int lo = w & 0xFFFFu;
  const unsigned int ex = (lo >> 7) & 0xFFu;
  if (lo != 0u && ex >= 118u && ex <= 132u) atomicAdd(&cnt, 1);
  __syncthreads();
  if (threadIdx.x == 0) g_is_bf16 = (cnt >= 200) ? 1 : 0;
}

// ---------------- C1: convert x (4 elems/thread) ------------------------------
__global__ void conv_x_kernel(const void* __restrict__ x)
{
  const int t = blockIdx.x * blockDim.x + threadIdx.x;
  if (t >= V_NODES * D_FEAT / 4) return;
  if (g_is_bf16) {
    reinterpret_cast<u16x4*>(g_xbf)[t] = reinterpret_cast<const u16x4*>(x)[t];
  } else {
    const float4 v = reinterpret_cast<const float4*>(x)[t];
    u16x4 o; o.x = f2b(v.x); o.y = f2b(v.y); o.z = f2b(v.z); o.w = f2b(v.w);
    reinterpret_cast<u16x4*>(g_xbf)[t] = o;
  }
}

// ---------------- C2: convert all small tensors -------------------------------
__global__ void conv_small_kernel(
    const void* p0, const void* p1, const void* p2, const void* p3,
    const void* p4, const void* p5, const void* p6, const void* p7)
{
  const int i = blockIdx.x * blockDim.x + threadIdx.x;
  if (i >= SMALL_TOTAL) return;
  const int offs[9] = {OFF_WEDGE, OFF_WPROJ, OFF_WIH, OFF_WHH,
                       OFF_BEDGE, OFF_BPROJ, OFF_BIH, OFF_BHH, SMALL_TOTAL};
  const void* ps[8] = {p0, p1, p2, p3, p4, p5, p6, p7};
  int r = 0;
#pragma unroll
  for (int k = 0; k < 8; k++) if (i >= offs[k]) r = k;
  const int j = i - offs[r];
  const unsigned short v = g_is_bf16
      ? reinterpret_cast<const unsigned short*>(ps[r])[j]
      : f2b(reinterpret_cast<const float*>(ps[r])[j]);
  g_wsmall[i] = v;
}

// ---------------- K0: zero counts --------------------------------------------
__global__ void zero_counts_kernel() {
  int i = blockIdx.x * blockDim.x + threadIdx.x;
  if (i < V_NODES) g_counts[i] = 0;
}

// ---------------- K1: hv = x @ Wproj.T + b_proj ; pd = wd.x ; ps = ws.x -------
__global__ __launch_bounds__(64) void node_pre_kernel()
{
  const int tile = blockIdx.x;
  const int lane = threadIdx.x;
  const int col  = lane & 15;      // A: m index; C/D: n index
  const int quad = lane >> 4;
  const int arow = tile * 16 + col;
  const unsigned short* W_edge = g_wsmall + OFF_WEDGE;
  const unsigned short* W_proj = g_wsmall + OFF_WPROJ;

  bf16x8 a[4];
#pragma unroll
  for (int kk = 0; kk < 4; kk++)
    a[kk] = load_frag(g_xbf + arow * D_FEAT + kk * 32 + quad * 8);

  f32x4 acc[8];
#pragma unroll
  for (int j = 0; j < 8; j++) { acc[j][0]=0.f; acc[j][1]=0.f; acc[j][2]=0.f; acc[j][3]=0.f; }
  f32x4 acce; acce[0]=0.f; acce[1]=0.f; acce[2]=0.f; acce[3]=0.f;

#pragma unroll
  for (int kk = 0; kk < 4; kk++) {
    bf16x8 be = {0,0,0,0,0,0,0,0};
    if (col < 2)  // n=0 -> w_dst (W_edge[0:128]), n=1 -> w_src (W_edge[128:256])
      be = load_frag(W_edge + col * D_FEAT + kk * 32 + quad * 8);
    acce = __builtin_amdgcn_mfma_f32_16x16x32_bf16(a[kk], be, acce, 0, 0, 0);
#pragma unroll
    for (int j = 0; j < 8; j++) {
      bf16x8 b = load_frag(W_proj + (16 * j + col) * D_FEAT + kk * 32 + quad * 8);
      acc[j] = __builtin_amdgcn_mfma_f32_16x16x32_bf16(a[kk], b, acc[j], 0, 0, 0);
    }
  }

#pragma unroll
  for (int j = 0; j < 8; j++) {
    const int h = 16 * j + col;
    const float bp = b2f(g_wsmall[OFF_BPROJ + h]);
#pragma unroll
    for (int r = 0; r < 4; r++) {
      const int vrow = tile * 16 + quad * 4 + r;
      g_hv[vrow * D_FEAT + h] = f2b(acc[j][r] + bp);
    }
  }
  if (col == 0) {
#pragma unroll
    for (int r = 0; r < 4; r++) g_pd[tile * 16 + quad * 4 + r] = acce[r];
  } else if (col == 1) {
#pragma unroll
    for (int r = 0; r < 4; r++) g_ps[tile * 16 + quad * 4 + r] = acce[r];
  }
}

// ---------------- K2: histogram of dst ---------------------------------------
__global__ void hist_kernel(const int* __restrict__ dst, int E)
{
  int e = blockIdx.x * blockDim.x + threadIdx.x;
  if (e < E) atomicAdd(&g_counts[dst[e]], 1);
}

// ---------------- K3: single-block exclusive scan ----------------------------
__global__ void scan_kernel()
{
  __shared__ int lds[1024];
  const int tid = threadIdx.x;
  int carry = 0;
  for (int base = 0; base < V_NODES; base += 1024) {
    const int i = base + tid;
    const int v = (i < V_NODES) ? g_counts[i] : 0;
    lds[tid] = v;
    __syncthreads();
    for (int off = 1; off < 1024; off <<= 1) {
      int t = (tid >= off) ? lds[tid - off] : 0;
      __syncthreads();
      lds[tid] += t;
      __syncthreads();
    }
    const int excl = lds[tid] - v;
    if (i < V_NODES) { g_row_off[i] = carry + excl; g_cursor[i] = carry + excl; }
    const int total = lds[1023];
    __syncthreads();
    carry += total;
  }
  if (tid == 0) g_row_off[V_NODES] = carry;
}

// ---------------- K4: edge scatter (CSR fill + softmax numerator) ------------
__global__ void edge_scatter_kernel(
    const int* __restrict__ src, const int* __restrict__ dst, int E)
{
  int e = blockIdx.x * blockDim.x + threadIdx.x;
  if (e >= E) return;
  const int d = dst[e], sn = src[e];
  float logit = g_pd[d] + g_ps[sn] + b2f(g_wsmall[OFF_BEDGE]);
  logit = (logit >= 0.f) ? logit : 0.01f * logit;           // LeakyReLU(0.01)
  const float w = __expf(logit);                            // no max-sub: cancels
  const int pos = atomicAdd(&g_cursor[d], 1);
  g_s_src[pos] = sn;
  g_s_val[pos] = w;
}

// ---------------- K5: per-dst aggregation + elu -> context (bf16) ------------
__global__ __launch_bounds__(64) void aggregate_kernel()
{
  const int v = blockIdx.x;
  const int lane = threadIdx.x;        // lane handles cols 2*lane, 2*lane+1
  const int beg = g_row_off[v], end = g_row_off[v + 1];
  float accx = 0.f, accy = 0.f, ssum = 0.f;
  for (int i = beg; i < end; i++) {
    const int sn  = g_s_src[i];        // uniform across wave
    const float w = g_s_val[i];
    ssum += w;
    const unsigned int pair =
        *reinterpret_cast<const unsigned int*>(g_hv + sn * D_FEAT + lane * 2);
    accx += w * b2f((unsigned short)(pair & 0xFFFFu));
    accy += w * b2f((unsigned short)(pair >> 16));
  }
  const float inv = (end > beg) ? (1.0f / ssum) : 0.0f;     // empty segment -> c=0
  float c0 = accx * inv, c1 = accy * inv;
  c0 = (c0 > 0.f) ? c0 : (__expf(c0) - 1.f);                // elu
  c1 = (c1 > 0.f) ? c1 : (__expf(c1) - 1.f);
  const unsigned int outp = ((unsigned int)f2b(c1) << 16) | (unsigned int)f2b(c0);
  *reinterpret_cast<unsigned int*>(g_ctx + v * D_FEAT + lane * 2) = outp;
}

// ---------------- K6: GRUCell + relu, fused MFMA gates, f32 out --------------
__global__ __launch_bounds__(64) void gru_kernel(const float* __restrict__ xf32,
                                                 float* __restrict__ out)
{
  const int tile = blockIdx.x;
  const int lane = threadIdx.x;
  const int col  = lane & 15;
  const int quad = lane >> 4;
  const int arow = tile * 16 + col;
  const unsigned short* W_ih = g_wsmall + OFF_WIH;
  const unsigned short* W_hh = g_wsmall + OFF_WHH;

  bf16x8 ax[4], ac[4];
#pragma unroll
  for (int kk = 0; kk < 4; kk++) {
    ax[kk] = load_frag(g_xbf + arow * D_FEAT + kk * 32 + quad * 8);
    ac[kk] = load_frag(g_ctx + arow * D_FEAT + kk * 32 + quad * 8);
  }

  f32x4 rr[8], zz[8], ni[8], nh[8];

  // r = sigmoid(gi_r + gh_r): weight rows [0,128)
#pragma unroll
  for (int j = 0; j < 8; j++) {
    const int h = 16 * j + col;
    const float bi = b2f(g_wsmall[OFF_BIH + h]) + b2f(g_wsmall[OFF_BHH + h]);
    f32x4 acc; acc[0]=bi; acc[1]=bi; acc[2]=bi; acc[3]=bi;
#pragma unroll
    for (int kk = 0; kk < 4; kk++) {
      bf16x8 b = load_frag(W_ih + h * D_FEAT + kk * 32 + quad * 8);
      acc = __builtin_amdgcn_mfma_f32_16x16x32_bf16(ac[kk], b, acc, 0, 0, 0);
    }
#pragma unroll
    for (int kk = 0; kk < 4; kk++) {
      bf16x8 b = load_frag(W_hh + h * D_FEAT + kk * 32 + quad * 8);
      acc = __builtin_amdgcn_mfma_f32_16x16x32_bf16(ax[kk], b, acc, 0, 0, 0);
    }
#pragma unroll
    for (int r = 0; r < 4; r++) rr[j][r] = 1.f / (1.f + __expf(-acc[r]));
  }

  // z = sigmoid(gi_z + gh_z): weight rows [128,256)
#pragma unroll
  for (int j = 0; j < 8; j++) {
    const int h = 16 * j + col;
    const float bi = b2f(g_wsmall[OFF_BIH + 128 + h]) + b2f(g_wsmall[OFF_BHH + 128 + h]);
    f32x4 acc; acc[0]=bi; acc[1]=bi; acc[2]=bi; acc[3]=bi;
#pragma unroll
    for (int kk = 0; kk < 4; kk++) {
      bf16x8 b = load_frag(W_ih + (128 + h) * D_FEAT + kk * 32 + quad * 8);
      acc = __builtin_amdgcn_mfma_f32_16x16x32_bf16(ac[kk], b, acc, 0, 0, 0);
    }
#pragma unroll
    for (int kk = 0; kk < 4; kk++) {
      bf16x8 b = load_frag(W_hh + (128 + h) * D_FEAT + kk * 32 + quad * 8);
      acc = __builtin_amdgcn_mfma_f32_16x16x32_bf16(ax[kk], b, acc, 0, 0, 0);
    }
#pragma unroll
    for (int r = 0; r < 4; r++) zz[j][r] = 1.f / (1.f + __expf(-acc[r]));
  }

  // n pieces: rows [256,384), kept separate (r gates only gh_n)
#pragma unroll
  for (int j = 0; j < 8; j++) {
    const int h = 16 * j + col;
    f32x4 ai; { const float b_ = b2f(g_wsmall[OFF_BIH + 256 + h]); ai[0]=b_; ai[1]=b_; ai[2]=b_; ai[3]=b_; }
    f32x4 ah; { const float b_ = b2f(g_wsmall[OFF_BHH + 256 + h]); ah[0]=b_; ah[1]=b_; ah[2]=b_; ah[3]=b_; }
#pragma unroll
    for (int kk = 0; kk < 4; kk++) {
      bf16x8 b = load_frag(W_ih + (256 + h) * D_FEAT + kk * 32 + quad * 8);
      ai = __builtin_amdgcn_mfma_f32_16x16x32_bf16(ac[kk], b, ai, 0, 0, 0);
    }
#pragma unroll
    for (int kk = 0; kk < 4; kk++) {
      bf16x8 b = load_frag(W_hh + (256 + h) * D_FEAT + kk * 32 + quad * 8);
      ah = __builtin_amdgcn_mfma_f32_16x16x32_bf16(ax[kk], b, ah, 0, 0, 0);
    }
    ni[j] = ai; nh[j] = ah;
  }

  // combine gates, relu (NaN-propagating), f32 store; residual from f32 x
  const int isb = g_is_bf16;
#pragma unroll
  for (int j = 0; j < 8; j++) {
    const int h = 16 * j + col;
#pragma unroll
    for (int r = 0; r < 4; r++) {
      const int vrow = tile * 16 + quad * 4 + r;
      const float n  = tanhf(ni[j][r] + rr[j][r] * nh[j][r]);
      const float z  = zz[j][r];
      const float xv = isb ? b2f(g_xbf[vrow * D_FEAT + h]) : xf32[vrow * D_FEAT + h];
      const float hn = (1.f - z) * n + z * xv;
      out[vrow * D_FEAT + h] = (hn < 0.f) ? 0.f : hn;  // relu; NaN passes (canary)
    }
  }
}

// ---------------- launch ------------------------------------------------------
extern "C" void kernel_launch(void* const* d_in, const int* in_sizes, int n_in,
                              void* d_out, int out_size, void* d_ws, size_t ws_size,
                              hipStream_t stream)
{
  (void)d_ws; (void)ws_size; (void)out_size;

  // resolve inputs by element count (same-size pairs keep dict order)
  int ix = -1, iWe = -1, ibe = -1, iWp = -1, ibp = -1,
      iWih = -1, iWhh = -1, ibih = -1, ibhh = -1, isrc = -1, idst = -1;
  for (int i = 0; i < n_in; i++) {
    const int s = in_sizes[i];
    if      (s == 6400000) ix = i;
    else if (s == 256)     iWe = i;
    else if (s == 1)       ibe = i;
    else if (s == 16384)   iWp = i;
    else if (s == 128)     ibp = i;
    else if (s == 49152)   { if (iWih < 0) iWih = i; else iWhh = i; }
    else if (s == 384)     { if (ibih < 0) ibih = i; else ibhh = i; }
    else if (s == 800000)  { if (isrc < 0) isrc = i; else idst = i; }
  }
  if (ix < 0 || iWe < 0 || ibe < 0 || iWp < 0 || ibp < 0 || iWih < 0 ||
      iWhh < 0 || ibih < 0 || ibhh < 0 || isrc < 0 || idst < 0) {
    ix = 0; iWe = 1; ibe = 2; iWp = 3; ibp = 4;           // dict-order fallback
    iWih = 5; iWhh = 6; ibih = 7; ibhh = 8; isrc = 9; idst = 10;
  }

  const int* src = (const int*)d_in[isrc];
  const int* dst = (const int*)d_in[idst];
  float* out = (float*)d_out;

  probe_kernel<<<1, 256, 0, stream>>>((const unsigned int*)d_in[ix]);
  conv_x_kernel<<<V_NODES * D_FEAT / 4 / 256, 256, 0, stream>>>(d_in[ix]);
  conv_small_kernel<<<(SMALL_TOTAL + 255) / 256, 256, 0, stream>>>(
      d_in[iWe], d_in[iWp], d_in[iWih], d_in[iWhh],
      d_in[ibe], d_in[ibp], d_in[ibih], d_in[ibhh]);
  zero_counts_kernel<<<(V_NODES + 255) / 256, 256, 0, stream>>>();
  node_pre_kernel<<<V_NODES / 16, 64, 0, stream>>>();
  hist_kernel<<<E_EDGES / 256, 256, 0, stream>>>(dst, E_EDGES);
  scan_kernel<<<1, 1024, 0, stream>>>();
  edge_scatter_kernel<<<E_EDGES / 256, 256, 0, stream>>>(src, dst, E_EDGES);
  aggregate_kernel<<<V_NODES, 64, 0, stream>>>();
  gru_kernel<<<V_NODES / 16, 64, 0, stream>>>((const float*)d_in[ix], out);
}